// Round 4
// baseline (517.507 us; speedup 1.0000x reference)
//
#include <hip/hip_runtime.h>
#include <math.h>

#define VOCAB   50265
#define D       768
#define N_NEW   200
#define N_NODES 199
#define N_EDGES 1024
#define LEAKY   0.2f

// ---- GEMM split-K config ----
#define ROW_T 4
#define KC    4
#define KLEN  192                       // 768/KC
#define NROWT 50                        // ceil(199/4)
#define NB_GEMM (NROWT * 3 * KC)        // 600
#define GAT_BLOCKS (NB_GEMM + N_NODES)  // 799

#define AQ     __ATOMIC_ACQUIRE
#define RL     __ATOMIC_RELEASE
#define ARL    __ATOMIC_ACQ_REL
#define AGENT  __HIP_MEMORY_SCOPE_AGENT

// counters in ws: [0]=gemm_done [1]=node_done [2]=softmax_flag [3]=agg_done
__global__ __launch_bounds__(256) void mega_kernel(
    const int* __restrict__ x,
    const float* __restrict__ orig_emb,
    const float* __restrict__ new_emb,
    const float* __restrict__ W,
    const float* __restrict__ a_src,
    const float* __restrict__ a_dst,
    const int* __restrict__ edge_index,
    float* __restrict__ out,
    unsigned* __restrict__ cnt,
    float* __restrict__ partial, float* __restrict__ h,
    float* __restrict__ sv, float* __restrict__ dv,
    float* __restrict__ alpha, float* __restrict__ gfeats,
    int* __restrict__ csr_off, int* __restrict__ csr_eid,
    int ntok)
{
    __shared__ __align__(16) unsigned char smem[13440];
    __shared__ float redS[4], redD[4];
    __shared__ int s_leader;
    const int tid = threadIdx.x;
    const int bid = blockIdx.x;

    // ================= GEMM blocks =================
    if (bid < NB_GEMM) {
        float (*fts)[KLEN] = (float (*)[KLEN])smem;
        const int rowt = bid % NROWT;
        const int colt = (bid / NROWT) % 3;
        const int kc   = bid / (NROWT * 3);
        const int row0 = rowt * ROW_T;
        const int col  = colt * 256 + tid;
        const int k0   = kc * KLEN;

        for (int i = tid; i < ROW_T * KLEN; i += 256) {
            int r  = i / KLEN;
            int kk = i - r * KLEN;
            int row = row0 + r;
            fts[r][kk] = (row < N_NODES) ? new_emb[(size_t)(1 + row) * D + k0 + kk] : 0.f;
        }
        __syncthreads();

        float acc0 = 0.f, acc1 = 0.f, acc2 = 0.f, acc3 = 0.f;
        #pragma unroll 4
        for (int kk = 0; kk < KLEN; ++kk) {
            float w = W[(size_t)(k0 + kk) * D + col];
            acc0 = fmaf(fts[0][kk], w, acc0);
            acc1 = fmaf(fts[1][kk], w, acc1);
            acc2 = fmaf(fts[2][kk], w, acc2);
            acc3 = fmaf(fts[3][kk], w, acc3);
        }

        const size_t base = ((size_t)kc * N_NODES) * D + col;
        if (row0 + 0 < N_NODES) partial[base + (size_t)(row0 + 0) * D] = acc0;
        if (row0 + 1 < N_NODES) partial[base + (size_t)(row0 + 1) * D] = acc1;
        if (row0 + 2 < N_NODES) partial[base + (size_t)(row0 + 2) * D] = acc2;
        if (row0 + 3 < N_NODES) partial[base + (size_t)(row0 + 3) * D] = acc3;

        __syncthreads();
        __threadfence();
        if (tid == 0) __hip_atomic_fetch_add(&cnt[0], 1u, RL, AGENT);
        return;
    }

    // ================= Node blocks =================
    if (bid < GAT_BLOCKS) {
        const int n = bid - NB_GEMM;

        if (tid == 0) {
            while (__hip_atomic_load(&cnt[0], AQ, AGENT) < (unsigned)NB_GEMM)
                __builtin_amdgcn_s_sleep(2);
        }
        __syncthreads();
        __threadfence();   // invalidate local caches before reading partial

        // ---- reduce partials -> h[n], sv[n], dv[n] ----
        const size_t kcstride = (size_t)N_NODES * D;
        float hv[3];
        #pragma unroll
        for (int j = 0; j < 3; ++j) {
            const size_t idx = (size_t)n * D + tid + j * 256;
            float s = partial[idx];
            s += partial[idx + kcstride];
            s += partial[idx + 2 * kcstride];
            s += partial[idx + 3 * kcstride];
            hv[j] = s;
            h[idx] = s;
        }
        float ps = hv[0] * a_src[tid] + hv[1] * a_src[tid + 256] + hv[2] * a_src[tid + 512];
        float pd = hv[0] * a_dst[tid] + hv[1] * a_dst[tid + 256] + hv[2] * a_dst[tid + 512];
        #pragma unroll
        for (int off = 32; off; off >>= 1) {
            ps += __shfl_down(ps, off, 64);
            pd += __shfl_down(pd, off, 64);
        }
        if ((tid & 63) == 0) { redS[tid >> 6] = ps; redD[tid >> 6] = pd; }
        __syncthreads();
        if (tid == 0) {
            sv[n] = redS[0] + redS[1] + redS[2] + redS[3];
            dv[n] = redD[0] + redD[1] + redD[2] + redD[3];
            __threadfence();
            unsigned prev = __hip_atomic_fetch_add(&cnt[1], 1u, ARL, AGENT);
            s_leader = (prev == (unsigned)(N_NODES - 1));
        }
        __syncthreads();

        if (s_leader) {
            // ---- softmax + CSR build (this block saw all sv/dv) ----
            __threadfence();
            float* e      = (float*)(smem);            // 4096
            short* sdst   = (short*)(smem + 4096);     // 2048
            float* m      = (float*)(smem + 6144);     // 800
            float* denom  = (float*)(smem + 6944);     // 800
            int*   off    = (int*)  (smem + 7744);     // 800
            int*   cursor = (int*)  (smem + 8544);     // 800
            int*   eid    = (int*)  (smem + 9344);     // 4096

            for (int i = tid; i < N_NODES; i += 256) cursor[i] = 0;
            __syncthreads();
            for (int k = tid; k < N_EDGES; k += 256) {
                int s = edge_index[k];
                int d = edge_index[N_EDGES + k];
                sdst[k] = (short)d;
                float ev = sv[s] + dv[d];
                e[k] = ev > 0.f ? ev : LEAKY * ev;
                atomicAdd(&cursor[d], 1);
            }
            __syncthreads();
            if (tid == 0) {
                int run = 0;
                for (int i = 0; i < N_NODES; ++i) { off[i] = run; run += cursor[i]; }
                off[N_NODES] = run;
            }
            __syncthreads();
            for (int i = tid; i < N_NODES; i += 256) cursor[i] = off[i];
            __syncthreads();
            for (int k = tid; k < N_EDGES; k += 256) {
                int pos = atomicAdd(&cursor[(int)sdst[k]], 1);
                eid[pos] = k;
            }
            __syncthreads();
            for (int i = tid; i < N_NODES; i += 256) {
                float mx = -INFINITY;
                for (int p = off[i]; p < off[i + 1]; ++p) mx = fmaxf(mx, e[eid[p]]);
                float dn = 0.f;
                for (int p = off[i]; p < off[i + 1]; ++p) dn += expf(e[eid[p]] - mx);
                m[i] = mx;
                denom[i] = dn;
            }
            __syncthreads();
            for (int k = tid; k < N_EDGES; k += 256) {
                int d = (int)sdst[k];
                alpha[k] = expf(e[k] - m[d]) / fmaxf(denom[d], 1e-9f);
            }
            for (int i = tid; i < N_NODES + 1; i += 256) csr_off[i] = off[i];
            for (int k = tid; k < N_EDGES; k += 256)     csr_eid[k] = eid[k];
            __syncthreads();
            __threadfence();
            if (tid == 0) __hip_atomic_store(&cnt[2], 1u, RL, AGENT);
        } else {
            if (tid == 0) {
                while (__hip_atomic_load(&cnt[2], AQ, AGENT) == 0u)
                    __builtin_amdgcn_s_sleep(2);
            }
            __syncthreads();
            __threadfence();
        }

        // ---- aggregate + elu + residual -> gfeats[n] ----
        const int p0 = csr_off[n], p1 = csr_off[n + 1];
        float a0 = 0.f, a1 = 0.f, a2 = 0.f;
        for (int p = p0; p < p1; ++p) {
            const int k = csr_eid[p];
            const float a = alpha[k];
            const float* hs = h + (size_t)edge_index[k] * D;
            a0 = fmaf(a, hs[tid], a0);
            a1 = fmaf(a, hs[tid + 256], a1);
            a2 = fmaf(a, hs[tid + 512], a2);
        }
        const float* f = new_emb + (size_t)(1 + n) * D;
        float e0 = a0 > 0.f ? a0 : expf(a0) - 1.f;
        float e1 = a1 > 0.f ? a1 : expf(a1) - 1.f;
        float e2 = a2 > 0.f ? a2 : expf(a2) - 1.f;
        gfeats[(size_t)n * D + tid]       = e0 + f[tid];
        gfeats[(size_t)n * D + tid + 256] = e1 + f[tid + 256];
        gfeats[(size_t)n * D + tid + 512] = e2 + f[tid + 512];

        __syncthreads();
        __threadfence();
        if (tid == 0) __hip_atomic_fetch_add(&cnt[3], 1u, RL, AGENT);
        return;
    }

    // ================= Gather blocks =================
    const int token = (bid - GAT_BLOCKS) * 4 + (tid >> 6);
    if (token >= ntok) return;
    const int lane = tid & 63;
    const int idx = x[token];

    const float4* src;
    if (idx < VOCAB) {
        src = (const float4*)(orig_emb + (size_t)idx * D);
    } else if (idx < VOCAB + N_NODES) {
        // wait for graph features (acquire per lane; wave-uniform)
        while (__hip_atomic_load(&cnt[3], AQ, AGENT) < (unsigned)N_NODES)
            __builtin_amdgcn_s_sleep(2);
        src = (const float4*)(gfeats + (size_t)(idx - VOCAB) * D);
    } else {
        src = (const float4*)(new_emb + (size_t)N_NEW * D);
    }

    float4* dst = (float4*)(out + (size_t)token * D);
    dst[lane]       = src[lane];
    dst[lane + 64]  = src[lane + 64];
    dst[lane + 128] = src[lane + 128];
}

extern "C" void kernel_launch(void* const* d_in, const int* in_sizes, int n_in,
                              void* d_out, int out_size, void* d_ws, size_t ws_size,
                              hipStream_t stream) {
    const int*   x        = (const int*)  d_in[0];
    const float* orig_emb = (const float*)d_in[1];
    const float* new_emb  = (const float*)d_in[2];
    const float* W        = (const float*)d_in[3];
    const float* a_src    = (const float*)d_in[4];
    const float* a_dst    = (const float*)d_in[5];
    const int*   edge_idx = (const int*)  d_in[6];
    float* out = (float*)d_out;

    // workspace layout
    unsigned* cnt  = (unsigned*)d_ws;                     // 4 counters (zeroed below)
    float* base    = (float*)((char*)d_ws + 256);
    float* partial = base;                                // 4*199*768
    float* h       = partial + (size_t)KC * N_NODES * D;  // 199*768
    float* sv      = h + (size_t)N_NODES * D;             // 199
    float* dv      = sv + N_NODES;                        // 199
    float* alpha   = dv + N_NODES;                        // 1024
    float* gfeats  = alpha + N_EDGES;                     // 199*768
    int*   csr_off = (int*)(gfeats + (size_t)N_NODES * D);// 200
    int*   csr_eid = csr_off + (N_NODES + 1);             // 1024

    const int ntok = in_sizes[0];                         // 32768
    const int nblocks = GAT_BLOCKS + (ntok + 3) / 4;      // 799 + 8192

    hipMemsetAsync(cnt, 0, 64, stream);
    mega_kernel<<<nblocks, 256, 0, stream>>>(
        x, orig_emb, new_emb, W, a_src, a_dst, edge_idx, out,
        cnt, partial, h, sv, dv, alpha, gfeats, csr_off, csr_eid, ntok);
}

// Round 5
// 79.164 us; speedup vs baseline: 6.5372x; 6.5372x over previous
//
#include <hip/hip_runtime.h>
#include <math.h>

#define VOCAB   50265
#define D       768
#define N_NEW   200
#define N_NODES 199
#define N_EDGES 1024
#define LEAKY   0.2f

// ---------------- Kernel 1: h = feats @ W  (+ per-chunk partial dots)
// grid (199 rows, 3 col-chunks), 256 threads. W is L2-resident (2.36 MB),
// reused by all 199 row-blocks of the same chunk.
__global__ __launch_bounds__(256) void gemm_h_kernel(
    const float* __restrict__ new_emb, const float* __restrict__ W,
    const float* __restrict__ a_src, const float* __restrict__ a_dst,
    float* __restrict__ h, float* __restrict__ svp, float* __restrict__ dvp)
{
    __shared__ float fts[D];          // 3 KB: one feats row
    __shared__ float rS[4], rD[4];
    const int tid = threadIdx.x;
    const int row = blockIdx.x;
    const int col = blockIdx.y * 256 + tid;

    for (int k = tid; k < D; k += 256)
        fts[k] = new_emb[(size_t)(1 + row) * D + k];
    __syncthreads();

    float acc = 0.f;
    #pragma unroll 8
    for (int k = 0; k < D; ++k)
        acc = fmaf(fts[k], W[(size_t)k * D + col], acc);

    h[(size_t)row * D + col] = acc;

    float ps = acc * a_src[col];
    float pd = acc * a_dst[col];
    #pragma unroll
    for (int off = 32; off; off >>= 1) {
        ps += __shfl_down(ps, off, 64);
        pd += __shfl_down(pd, off, 64);
    }
    if ((tid & 63) == 0) { rS[tid >> 6] = ps; rD[tid >> 6] = pd; }
    __syncthreads();
    if (tid == 0) {
        svp[row * 3 + blockIdx.y] = rS[0] + rS[1] + rS[2] + rS[3];
        dvp[row * 3 + blockIdx.y] = rD[0] + rD[1] + rD[2] + rD[3];
    }
}

// ---------------- Kernel 2: fused edge-softmax + aggregate (one block per node)
// Every block redundantly computes sv/dv and all edge scores in LDS (cheap,
// fully parallel across blocks), builds an ORDERED list of its own edges via
// prefix scan (deterministic), then aggregates.
__global__ __launch_bounds__(256) void softagg_kernel(
    const int* __restrict__ edge_index, const float* __restrict__ svp,
    const float* __restrict__ dvp, const float* __restrict__ h,
    const float* __restrict__ new_emb, float* __restrict__ gfeats)
{
    __shared__ float sv_l[N_NODES], dv_l[N_NODES];
    __shared__ float e[N_EDGES];
    __shared__ short ssrc[N_EDGES];
    __shared__ short ml[N_EDGES];
    __shared__ int   wsum[4];
    __shared__ int   s_total;
    const int n   = blockIdx.x;
    const int tid = threadIdx.x;
    const int lane = tid & 63, wid = tid >> 6;

    for (int i = tid; i < N_NODES; i += 256) {
        sv_l[i] = svp[3 * i] + svp[3 * i + 1] + svp[3 * i + 2];
        dv_l[i] = dvp[3 * i] + dvp[3 * i + 1] + dvp[3 * i + 2];
    }
    __syncthreads();

    // thread t owns edges [4t, 4t+4)
    const int4 se = ((const int4*)edge_index)[tid];
    const int4 de = ((const int4*)(edge_index + N_EDGES))[tid];
    const int srcs[4] = { se.x, se.y, se.z, se.w };
    const int dsts[4] = { de.x, de.y, de.z, de.w };

    int mycnt = 0;
    #pragma unroll
    for (int j = 0; j < 4; ++j) {
        const int k = 4 * tid + j;
        float ev = sv_l[srcs[j]] + dv_l[dsts[j]];
        e[k] = ev > 0.f ? ev : LEAKY * ev;
        ssrc[k] = (short)srcs[j];
        if (dsts[j] == n) ++mycnt;
    }

    // exclusive prefix of mycnt over 256 threads (wave scan + wave offsets)
    int pre = mycnt;
    #pragma unroll
    for (int off = 1; off < 64; off <<= 1) {
        int v = __shfl_up(pre, off, 64);
        if (lane >= off) pre += v;
    }
    if (lane == 63) wsum[wid] = pre;
    __syncthreads();
    int woff = 0;
    for (int w = 0; w < wid; ++w) woff += wsum[w];
    int base = woff + pre - mycnt;
    #pragma unroll
    for (int j = 0; j < 4; ++j) {
        if (dsts[j] == n) ml[base++] = (short)(4 * tid + j);
    }
    if (tid == 255) s_total = woff + pre;
    __syncthreads();

    const int c = s_total;

    // redundant (deterministic) max/denom over this node's edges
    float mx = -INFINITY;
    for (int p = 0; p < c; ++p) mx = fmaxf(mx, e[ml[p]]);
    float dn = 0.f;
    for (int p = 0; p < c; ++p) dn += expf(e[ml[p]] - mx);
    const float inv = 1.f / fmaxf(dn, 1e-9f);

    float a0 = 0.f, a1 = 0.f, a2 = 0.f;
    for (int p = 0; p < c; ++p) {
        const int k = ml[p];
        const float a = expf(e[k] - mx) * inv;
        const float* hs = h + (size_t)ssrc[k] * D;
        a0 = fmaf(a, hs[tid], a0);
        a1 = fmaf(a, hs[tid + 256], a1);
        a2 = fmaf(a, hs[tid + 512], a2);
    }
    const float* f = new_emb + (size_t)(1 + n) * D;
    float e0 = a0 > 0.f ? a0 : expf(a0) - 1.f;
    float e1 = a1 > 0.f ? a1 : expf(a1) - 1.f;
    float e2 = a2 > 0.f ? a2 : expf(a2) - 1.f;
    gfeats[(size_t)n * D + tid]       = e0 + f[tid];
    gfeats[(size_t)n * D + tid + 256] = e1 + f[tid + 256];
    gfeats[(size_t)n * D + tid + 512] = e2 + f[tid + 512];
}

// ---------------- Kernel 3: gather. One wave per token, 3 float4/lane.
__global__ __launch_bounds__(256) void gather_kernel(
    const int* __restrict__ x, const float* __restrict__ orig_emb,
    const float* __restrict__ gfeats, const float* __restrict__ new_emb,
    float* __restrict__ out, int ntok)
{
    const int token = blockIdx.x * 4 + (threadIdx.x >> 6);
    if (token >= ntok) return;
    const int lane = threadIdx.x & 63;
    const int idx = x[token];

    const float4* src;
    if (idx < VOCAB)
        src = (const float4*)(orig_emb + (size_t)idx * D);
    else if (idx < VOCAB + N_NODES)
        src = (const float4*)(gfeats + (size_t)(idx - VOCAB) * D);
    else
        src = (const float4*)(new_emb + (size_t)N_NEW * D);

    float4* dst = (float4*)(out + (size_t)token * D);
    dst[lane]       = src[lane];
    dst[lane + 64]  = src[lane + 64];
    dst[lane + 128] = src[lane + 128];
}

extern "C" void kernel_launch(void* const* d_in, const int* in_sizes, int n_in,
                              void* d_out, int out_size, void* d_ws, size_t ws_size,
                              hipStream_t stream) {
    const int*   x        = (const int*)  d_in[0];
    const float* orig_emb = (const float*)d_in[1];
    const float* new_emb  = (const float*)d_in[2];
    const float* W        = (const float*)d_in[3];
    const float* a_src    = (const float*)d_in[4];
    const float* a_dst    = (const float*)d_in[5];
    const int*   edge_idx = (const int*)  d_in[6];
    float* out = (float*)d_out;

    // workspace layout (floats) — no zero-init needed, everything fully written
    float* ws     = (float*)d_ws;
    float* h      = ws;                               // 199*768
    float* svp    = h + (size_t)N_NODES * D;          // 199*3
    float* dvp    = svp + N_NODES * 3;                // 199*3
    float* gfeats = dvp + N_NODES * 3;                // 199*768

    const int ntok = in_sizes[0];                     // 32768

    gemm_h_kernel<<<dim3(N_NODES, 3), 256, 0, stream>>>(
        new_emb, W, a_src, a_dst, h, svp, dvp);
    softagg_kernel<<<N_NODES, 256, 0, stream>>>(
        edge_idx, svp, dvp, h, new_emb, gfeats);
    gather_kernel<<<(ntok + 3) / 4, 256, 0, stream>>>(
        x, orig_emb, gfeats, new_emb, out, ntok);
}

// Round 6
// 62.204 us; speedup vs baseline: 8.3195x; 1.2727x over previous
//
#include <hip/hip_runtime.h>
#include <math.h>

#define VOCAB   50265
#define D       768
#define N_NEW   200
#define N_NODES 199
#define N_EDGES 1024
#define LEAKY   0.2f

// ---- GEMM split-K config ----
#define ROW_T 4
#define KC    4
#define KLEN  192                 // 768/KC
#define NROWT 50                  // ceil(199/4)
// partial[kc][row][col]  (KC * 199 * 768 floats)
// svp/dvp[row][kc*3+colt] (199 * 12 floats)

// ---------------- Kernel 1: split-K GEMM partials + split partial dots
__global__ __launch_bounds__(256) void gemm_partial_kernel(
    const float* __restrict__ new_emb, const float* __restrict__ W,
    const float* __restrict__ a_src, const float* __restrict__ a_dst,
    float* __restrict__ partial, float* __restrict__ svp, float* __restrict__ dvp)
{
    __shared__ float fts[ROW_T][KLEN];       // 3 KB
    __shared__ float rS[ROW_T][4], rD[ROW_T][4];
    const int tid  = threadIdx.x;
    const int rowt = blockIdx.x;
    const int colt = blockIdx.y;
    const int kc   = blockIdx.z;
    const int row0 = rowt * ROW_T;
    const int col  = colt * 256 + tid;
    const int k0   = kc * KLEN;
    const int lane = tid & 63, wid = tid >> 6;

    for (int i = tid; i < ROW_T * KLEN; i += 256) {
        int r  = i / KLEN;
        int kk = i - r * KLEN;
        int row = row0 + r;
        fts[r][kk] = (row < N_NODES) ? new_emb[(size_t)(1 + row) * D + k0 + kk] : 0.f;
    }
    __syncthreads();

    float acc[ROW_T] = {0.f, 0.f, 0.f, 0.f};
    #pragma unroll 4
    for (int kk = 0; kk < KLEN; ++kk) {
        float w = W[(size_t)(k0 + kk) * D + col];
        #pragma unroll
        for (int r = 0; r < ROW_T; ++r)
            acc[r] = fmaf(fts[r][kk], w, acc[r]);
    }

    const size_t base = ((size_t)kc * N_NODES) * D + col;
    #pragma unroll
    for (int r = 0; r < ROW_T; ++r)
        if (row0 + r < N_NODES) partial[base + (size_t)(row0 + r) * D] = acc[r];

    // split partial dots: this block's 256-col contribution to h[row].a_src/.a_dst
    const float as = a_src[col];
    const float ad = a_dst[col];
    #pragma unroll
    for (int r = 0; r < ROW_T; ++r) {
        float ps = acc[r] * as;
        float pd = acc[r] * ad;
        #pragma unroll
        for (int off = 32; off; off >>= 1) {
            ps += __shfl_down(ps, off, 64);
            pd += __shfl_down(pd, off, 64);
        }
        if (lane == 0) { rS[r][wid] = ps; rD[r][wid] = pd; }
    }
    __syncthreads();
    if (tid < ROW_T) {
        const int row = row0 + tid;
        if (row < N_NODES) {
            const int slot = row * 12 + kc * 3 + colt;
            svp[slot] = rS[tid][0] + rS[tid][1] + rS[tid][2] + rS[tid][3];
            dvp[slot] = rD[tid][0] + rD[tid][1] + rD[tid][2] + rD[tid][3];
        }
    }
}

// ---------------- Kernel 2: gather with fused GAT finish for graph tokens
// One wave per token. Non-graph tokens: plain 3x float4 copy.
// Graph tokens: find in-edges (ballot scan, deterministic), softmax from
// svp/dvp partial sums, aggregate from split-K partials, elu + residual.
__global__ __launch_bounds__(256) void gather_fused_kernel(
    const int* __restrict__ x, const float* __restrict__ orig_emb,
    const float* __restrict__ new_emb, const int* __restrict__ edge_index,
    const float* __restrict__ partial, const float* __restrict__ svp,
    const float* __restrict__ dvp, float* __restrict__ out, int ntok)
{
    __shared__ int mlist[4][32];
    const int tid   = threadIdx.x;
    const int token = blockIdx.x * 4 + (tid >> 6);
    if (token >= ntok) return;
    const int lane = tid & 63;
    const int wid  = tid >> 6;
    const int idx  = x[token];

    float4* dst = (float4*)(out + (size_t)token * D);

    if (idx < VOCAB) {
        const float4* src = (const float4*)(orig_emb + (size_t)idx * D);
        dst[lane]       = src[lane];
        dst[lane + 64]  = src[lane + 64];
        dst[lane + 128] = src[lane + 128];
        return;
    }
    if (idx >= VOCAB + N_NODES) {
        const float4* src = (const float4*)(new_emb + (size_t)N_NEW * D);
        dst[lane]       = src[lane];
        dst[lane + 64]  = src[lane + 64];
        dst[lane + 128] = src[lane + 128];
        return;
    }

    // ---- graph token: node n ----
    const int n = idx - VOCAB;

    // 1) scan dst list for in-edges of n (deterministic order: j-major, i, lane)
    int cnt = 0;
    for (int j = 0; j < 4; ++j) {
        const int4 d4 = ((const int4*)(edge_index + N_EDGES))[j * 64 + lane];
        const int dd[4] = { d4.x, d4.y, d4.z, d4.w };
        #pragma unroll
        for (int i = 0; i < 4; ++i) {
            const unsigned long long mask = __ballot(dd[i] == n);
            if (dd[i] == n) {
                int pos = cnt + __popcll(mask & ((1ull << lane) - 1ull));
                if (pos < 32) mlist[wid][pos] = j * 256 + lane * 4 + i;
            }
            cnt += __popcll(mask);
        }
    }
    const int c = min(cnt, 32);

    float4 acc0 = {0.f, 0.f, 0.f, 0.f};
    float4 acc1 = {0.f, 0.f, 0.f, 0.f};
    float4 acc2 = {0.f, 0.f, 0.f, 0.f};

    if (c > 0) {
        // 2) dv[n] (all lanes, broadcast loads)
        float dvn = 0.f;
        #pragma unroll
        for (int q = 0; q < 12; ++q) dvn += dvp[n * 12 + q];

        // 3) per-lane edge scores
        float e = -INFINITY;
        int   srcp = 0;
        if (lane < c) {
            const int k = mlist[wid][lane];
            srcp = edge_index[k];
            float sv = 0.f;
            #pragma unroll
            for (int q = 0; q < 12; ++q) sv += svp[srcp * 12 + q];
            const float ev = sv + dvn;
            e = ev > 0.f ? ev : LEAKY * ev;
        }
        float m = e;
        #pragma unroll
        for (int off = 32; off; off >>= 1)
            m = fmaxf(m, __shfl_xor(m, off, 64));
        float ex = (lane < c) ? expf(e - m) : 0.f;
        float dn = ex;
        #pragma unroll
        for (int off = 32; off; off >>= 1)
            dn += __shfl_xor(dn, off, 64);
        const float alpha = ex / fmaxf(dn, 1e-9f);

        // 4) aggregate: acc += alpha_p * h[src_p], h reconstructed from partials
        const int kstr = N_NODES * D / 4;     // float4 stride between kc chunks
        for (int p = 0; p < c; ++p) {
            const float a = __shfl(alpha, p, 64);
            const int   s = __shfl(srcp,  p, 64);
            const float4* pb = (const float4*)(partial + (size_t)s * D);
            #pragma unroll
            for (int ch = 0; ch < 3; ++ch) {
                const int o = ch * 64 + lane;
                float4 h0 = pb[o];
                float4 h1 = pb[o + kstr];
                float4 h2 = pb[o + 2 * kstr];
                float4 h3 = pb[o + 3 * kstr];
                const float hx = h0.x + h1.x + h2.x + h3.x;
                const float hy = h0.y + h1.y + h2.y + h3.y;
                const float hz = h0.z + h1.z + h2.z + h3.z;
                const float hw = h0.w + h1.w + h2.w + h3.w;
                float4* ac = (ch == 0) ? &acc0 : (ch == 1) ? &acc1 : &acc2;
                ac->x = fmaf(a, hx, ac->x);
                ac->y = fmaf(a, hy, ac->y);
                ac->z = fmaf(a, hz, ac->z);
                ac->w = fmaf(a, hw, ac->w);
            }
        }
    }

    // 5) elu + residual, store
    const float4* f4 = (const float4*)(new_emb + (size_t)(1 + n) * D);
    float4 accs[3] = {acc0, acc1, acc2};
    #pragma unroll
    for (int ch = 0; ch < 3; ++ch) {
        const int o = ch * 64 + lane;
        const float4 r = f4[o];
        float4 v;
        v.x = (accs[ch].x > 0.f ? accs[ch].x : expf(accs[ch].x) - 1.f) + r.x;
        v.y = (accs[ch].y > 0.f ? accs[ch].y : expf(accs[ch].y) - 1.f) + r.y;
        v.z = (accs[ch].z > 0.f ? accs[ch].z : expf(accs[ch].z) - 1.f) + r.z;
        v.w = (accs[ch].w > 0.f ? accs[ch].w : expf(accs[ch].w) - 1.f) + r.w;
        dst[o] = v;
    }
}

extern "C" void kernel_launch(void* const* d_in, const int* in_sizes, int n_in,
                              void* d_out, int out_size, void* d_ws, size_t ws_size,
                              hipStream_t stream) {
    const int*   x        = (const int*)  d_in[0];
    const float* orig_emb = (const float*)d_in[1];
    const float* new_emb  = (const float*)d_in[2];
    const float* W        = (const float*)d_in[3];
    const float* a_src    = (const float*)d_in[4];
    const float* a_dst    = (const float*)d_in[5];
    const int*   edge_idx = (const int*)  d_in[6];
    float* out = (float*)d_out;

    // workspace layout (floats) — everything written before read
    float* ws      = (float*)d_ws;
    float* partial = ws;                                   // KC*199*768
    float* svp     = partial + (size_t)KC * N_NODES * D;   // 199*12
    float* dvp     = svp + N_NODES * 12;                   // 199*12

    const int ntok = in_sizes[0];                          // 32768

    gemm_partial_kernel<<<dim3(NROWT, 3, KC), 256, 0, stream>>>(
        new_emb, W, a_src, a_dst, partial, svp, dvp);
    gather_fused_kernel<<<(ntok + 3) / 4, 256, 0, stream>>>(
        x, orig_emb, new_emb, edge_idx, partial, svp, dvp, out, ntok);
}

// Round 8
// 58.233 us; speedup vs baseline: 8.8868x; 1.0682x over previous
//
#include <hip/hip_runtime.h>
#include <math.h>

#define VOCAB   50265
#define D       768
#define N_NEW   200
#define N_NODES 199
#define N_EDGES 1024
#define LEAKY   0.2f

typedef float f4 __attribute__((ext_vector_type(4)));

// ---- GEMM split-K config ----
#define ROW_T 4
#define KC    8
#define KLEN  96                  // 768/KC
#define NROWT 50                  // ceil(199/4)
#define NCH   (KC * 3)            // svp/dvp slots per row (24)
// partial[kc][row][col]  (KC * 199 * 768 floats)
// svp/dvp[row][kc*3+colt] (199 * 24 floats)

// ---------------- Kernel 1: split-K GEMM partials + split partial dots
__global__ __launch_bounds__(256) void gemm_partial_kernel(
    const float* __restrict__ new_emb, const float* __restrict__ W,
    const float* __restrict__ a_src, const float* __restrict__ a_dst,
    float* __restrict__ partial, float* __restrict__ svp, float* __restrict__ dvp)
{
    __shared__ float fts[ROW_T][KLEN];       // 1.5 KB
    __shared__ float rS[ROW_T][4], rD[ROW_T][4];
    const int tid  = threadIdx.x;
    const int rowt = blockIdx.x;
    const int colt = blockIdx.y;
    const int kc   = blockIdx.z;
    const int row0 = rowt * ROW_T;
    const int col  = colt * 256 + tid;
    const int k0   = kc * KLEN;
    const int lane = tid & 63, wid = tid >> 6;

    for (int i = tid; i < ROW_T * KLEN; i += 256) {
        int r  = i / KLEN;
        int kk = i - r * KLEN;
        int row = row0 + r;
        fts[r][kk] = (row < N_NODES) ? new_emb[(size_t)(1 + row) * D + k0 + kk] : 0.f;
    }
    __syncthreads();

    float acc[ROW_T] = {0.f, 0.f, 0.f, 0.f};
    #pragma unroll 4
    for (int kk = 0; kk < KLEN; ++kk) {
        float w = W[(size_t)(k0 + kk) * D + col];
        #pragma unroll
        for (int r = 0; r < ROW_T; ++r)
            acc[r] = fmaf(fts[r][kk], w, acc[r]);
    }

    const size_t base = ((size_t)kc * N_NODES) * D + col;
    #pragma unroll
    for (int r = 0; r < ROW_T; ++r)
        if (row0 + r < N_NODES) partial[base + (size_t)(row0 + r) * D] = acc[r];

    // split partial dots: this block's 256-col slice of h[row].a_src/.a_dst
    const float as = a_src[col];
    const float ad = a_dst[col];
    #pragma unroll
    for (int r = 0; r < ROW_T; ++r) {
        float ps = acc[r] * as;
        float pd = acc[r] * ad;
        #pragma unroll
        for (int off = 32; off; off >>= 1) {
            ps += __shfl_down(ps, off, 64);
            pd += __shfl_down(pd, off, 64);
        }
        if (lane == 0) { rS[r][wid] = ps; rD[r][wid] = pd; }
    }
    __syncthreads();
    if (tid < ROW_T) {
        const int row = row0 + tid;
        if (row < N_NODES) {
            const int slot = row * NCH + kc * 3 + colt;
            svp[slot] = rS[tid][0] + rS[tid][1] + rS[tid][2] + rS[tid][3];
            dvp[slot] = rD[tid][0] + rD[tid][1] + rD[tid][2] + rD[tid][3];
        }
    }
}

// ---------------- Kernel 2: gather with fused GAT finish for graph tokens
__global__ __launch_bounds__(256) void gather_fused_kernel(
    const int* __restrict__ x, const float* __restrict__ orig_emb,
    const float* __restrict__ new_emb, const int* __restrict__ edge_index,
    const float* __restrict__ partial, const float* __restrict__ svp,
    const float* __restrict__ dvp, float* __restrict__ out, int ntok)
{
    __shared__ int mlist[4][32];
    const int tid   = threadIdx.x;
    const int token = blockIdx.x * 4 + (tid >> 6);
    if (token >= ntok) return;
    const int lane = tid & 63;
    const int wid  = tid >> 6;
    const int idx = x[token];

    f4* dst = (f4*)(out + (size_t)token * D);

    if (idx < VOCAB) {
        const f4* src = (const f4*)(orig_emb + (size_t)idx * D);
        f4 v0 = src[lane];
        f4 v1 = src[lane + 64];
        f4 v2 = src[lane + 128];
        __builtin_nontemporal_store(v0, &dst[lane]);
        __builtin_nontemporal_store(v1, &dst[lane + 64]);
        __builtin_nontemporal_store(v2, &dst[lane + 128]);
        return;
    }
    if (idx >= VOCAB + N_NODES) {
        const f4* src = (const f4*)(new_emb + (size_t)N_NEW * D);
        f4 v0 = src[lane];
        f4 v1 = src[lane + 64];
        f4 v2 = src[lane + 128];
        __builtin_nontemporal_store(v0, &dst[lane]);
        __builtin_nontemporal_store(v1, &dst[lane + 64]);
        __builtin_nontemporal_store(v2, &dst[lane + 128]);
        return;
    }

    // ---- graph token: node n ----
    const int n = idx - VOCAB;

    // 1) scan dst list for in-edges of n (deterministic order)
    int cnt = 0;
    for (int j = 0; j < 4; ++j) {
        const int4 d4 = ((const int4*)(edge_index + N_EDGES))[j * 64 + lane];
        const int dd[4] = { d4.x, d4.y, d4.z, d4.w };
        #pragma unroll
        for (int i = 0; i < 4; ++i) {
            const unsigned long long mask = __ballot(dd[i] == n);
            if (dd[i] == n) {
                int pos = cnt + __popcll(mask & ((1ull << lane) - 1ull));
                if (pos < 32) mlist[wid][pos] = j * 256 + lane * 4 + i;
            }
            cnt += __popcll(mask);
        }
    }
    const int c = min(cnt, 32);

    f4 acc0 = {0.f, 0.f, 0.f, 0.f};
    f4 acc1 = {0.f, 0.f, 0.f, 0.f};
    f4 acc2 = {0.f, 0.f, 0.f, 0.f};

    if (c > 0) {
        // 2) dv[n]
        float dvn = 0.f;
        #pragma unroll
        for (int q = 0; q < NCH; ++q) dvn += dvp[n * NCH + q];

        // 3) per-lane edge scores
        float e = -INFINITY;
        int   srcp = 0;
        if (lane < c) {
            const int k = mlist[wid][lane];
            srcp = edge_index[k];
            float sv = 0.f;
            #pragma unroll
            for (int q = 0; q < NCH; ++q) sv += svp[srcp * NCH + q];
            const float ev = sv + dvn;
            e = ev > 0.f ? ev : LEAKY * ev;
        }
        float m = e;
        #pragma unroll
        for (int off = 32; off; off >>= 1)
            m = fmaxf(m, __shfl_xor(m, off, 64));
        float ex = (lane < c) ? expf(e - m) : 0.f;
        float dn = ex;
        #pragma unroll
        for (int off = 32; off; off >>= 1)
            dn += __shfl_xor(dn, off, 64);
        const float alpha = ex / fmaxf(dn, 1e-9f);

        // 4) aggregate: acc += alpha_p * h[src_p], h summed from KC chunks
        const int kstr = N_NODES * D / 4;     // f4 stride between kc chunks
        for (int p = 0; p < c; ++p) {
            const float a = __shfl(alpha, p, 64);
            const int   s = __shfl(srcp,  p, 64);
            const f4* pb = (const f4*)(partial + (size_t)s * D);
            #pragma unroll
            for (int ch = 0; ch < 3; ++ch) {
                const int o = ch * 64 + lane;
                f4 hsum = {0.f, 0.f, 0.f, 0.f};
                #pragma unroll
                for (int q = 0; q < KC; ++q)
                    hsum += pb[o + q * kstr];
                f4* ac = (ch == 0) ? &acc0 : (ch == 1) ? &acc1 : &acc2;
                *ac += a * hsum;
            }
        }
    }

    // 5) elu + residual, store
    const f4* f4p = (const f4*)(new_emb + (size_t)(1 + n) * D);
    f4 accs[3] = {acc0, acc1, acc2};
    #pragma unroll
    for (int ch = 0; ch < 3; ++ch) {
        const int o = ch * 64 + lane;
        const f4 r = f4p[o];
        f4 v;
        v.x = (accs[ch].x > 0.f ? accs[ch].x : expf(accs[ch].x) - 1.f) + r.x;
        v.y = (accs[ch].y > 0.f ? accs[ch].y : expf(accs[ch].y) - 1.f) + r.y;
        v.z = (accs[ch].z > 0.f ? accs[ch].z : expf(accs[ch].z) - 1.f) + r.z;
        v.w = (accs[ch].w > 0.f ? accs[ch].w : expf(accs[ch].w) - 1.f) + r.w;
        __builtin_nontemporal_store(v, &dst[o]);
    }
}

extern "C" void kernel_launch(void* const* d_in, const int* in_sizes, int n_in,
                              void* d_out, int out_size, void* d_ws, size_t ws_size,
                              hipStream_t stream) {
    const int*   x        = (const int*)  d_in[0];
    const float* orig_emb = (const float*)d_in[1];
    const float* new_emb  = (const float*)d_in[2];
    const float* W        = (const float*)d_in[3];
    const float* a_src    = (const float*)d_in[4];
    const float* a_dst    = (const float*)d_in[5];
    const int*   edge_idx = (const int*)  d_in[6];
    float* out = (float*)d_out;

    // workspace layout (floats) — everything written before read
    float* ws      = (float*)d_ws;
    float* partial = ws;                                   // KC*199*768
    float* svp     = partial + (size_t)KC * N_NODES * D;   // 199*NCH
    float* dvp     = svp + N_NODES * NCH;                  // 199*NCH

    const int ntok = in_sizes[0];                          // 32768

    gemm_partial_kernel<<<dim3(NROWT, 3, KC), 256, 0, stream>>>(
        new_emb, W, a_src, a_dst, partial, svp, dvp);
    gather_fused_kernel<<<(ntok + 3) / 4, 256, 0, stream>>>(
        x, orig_emb, new_emb, edge_idx, partial, svp, dvp, out, ntok);
}